// Round 17
// baseline (57.788 us; speedup 1.0000x reference)
//
#include <hip/hip_runtime.h>

typedef __attribute__((ext_vector_type(8))) short short8;
typedef __attribute__((ext_vector_type(4))) float f32x4;

#define CI    128
#define CO_   256
#define HW_   56
#define PLANE 3136
#define NB    16
#define STOT  50176
#define KTOT  1152
#define OUTN  802816   // CO_*PLANE
#define PLSZ  3211264ull   // one cb-plane of Xt2: 50176 rows x 64 B

// ws layout: [0, 12845056) Xt2 bf16, 4 planes [cb][S][64B] ; [12845056, +589824) Wpre ; 256B zeros
#define XT_BYTES   12845056ull
#define WP_USHORTS 294912
#define WS_NEED    (12845056ull + 589824ull + 256ull)

__device__ __forceinline__ unsigned short f2bf(float f) {
  unsigned u = __float_as_uint(f);
  u += 0x7FFFu + ((u >> 16) & 1u);   // RNE
  return (unsigned short)(u >> 16);
}

__device__ __forceinline__ void gload16(void* lds, const void* g) {
  __builtin_amdgcn_global_load_lds(
      (const __attribute__((address_space(1))) unsigned int*)g,
      (__attribute__((address_space(3))) unsigned int*)lds, 16, 0, 0);
}

template <int N> __device__ __forceinline__ void vmwait() {
  asm volatile("s_waitcnt vmcnt(%0)" ::"n"(N) : "memory");
}

// ---------------- fused prep: blocks 0..1599 = prep_x ; 1600..1743 = prep_w ----------------
// (both byte-identical to the verified R12/R15/R16 kernels)
__global__ __launch_bounds__(256) void prep_fused(const float* __restrict__ X,
                                                  const float* __restrict__ W,
                                                  unsigned short* __restrict__ Xt,
                                                  unsigned short* __restrict__ Wp) {
  const int t = threadIdx.x;
  if (blockIdx.x < 1600) {
    __shared__ __align__(16) unsigned short tile[32][132];
    const int bx = blockIdx.x;
    const int n   = bx / 100;
    const int rem = bx % 100;
    const int cib = rem / 25;          // == cb plane
    const int spb = rem % 25;
    const int sp0 = spb * 128;
    const float* src = X + (size_t)(n * CI + cib * 32) * PLANE;
#pragma unroll
    for (int j = 0; j < 4; ++j) {
      int f = t + 256 * j;
      int ci  = f >> 5;
      int sp4 = (f & 31) * 4;
      if (sp0 + sp4 < PLANE) {
        f32x4 v = *(const f32x4*)(src + (size_t)ci * PLANE + sp0 + sp4);
#pragma unroll
        for (int e = 0; e < 4; ++e) tile[ci][sp4 + e] = f2bf(v[e]);
      }
    }
    __syncthreads();
    unsigned short* dstp = Xt + (size_t)cib * (PLSZ / 2) + ((size_t)n * PLANE + sp0) * 32;
#pragma unroll
    for (int j = 0; j < 2; ++j) {
      int g = t + 256 * j;
      int sp = g >> 2;
      int q  = g & 3;
      if (sp0 + sp < PLANE) {
        short8 v;
#pragma unroll
        for (int e = 0; e < 8; ++e) v[e] = (short)tile[q * 8 + e][sp];
        *(short8*)(dstp + (size_t)sp * 32 + q * 8) = v;
      }
    }
  } else {
    const int u = (blockIdx.x - 1600) * 256 + t;   // 0..36863
    const int rcbmt = u >> 9;
    const int p     = u & 511;
    const int mt  = rcbmt & 1;
    const int rcb = rcbmt >> 1;
    const int cb  = rcb & 3;
    const int r   = rcb >> 2;
    const int col = p >> 2;
    const int kg  = (p & 3) ^ ((col >> 1) & 3);
    const int co  = mt * 128 + col;
    const int ci0 = cb * 32 + kg * 8;
    short8 v;
#pragma unroll
    for (int e = 0; e < 8; ++e)
      v[e] = (short)f2bf(W[(size_t)co * KTOT + (size_t)(ci0 + e) * 9 + r]);
    *(short8*)(Wp + (size_t)u * 8) = v;
    if (u < 16) {
      short8 z = {0, 0, 0, 0, 0, 0, 0, 0};
      *(short8*)(Wp + WP_USHORTS + u * 8) = z;
    }
  }
}

// ---------------- conv_gemm: 2-wave block 128co x 128sp, waves 64x128, ring-3, 3 blk/CU -----
// R17 = R16's high-intensity wave tile (64x128, 29.1 FLOP/LDS-byte) in R12's balanced
// geometry: 784 blocks (2mt x 392spt), 48KB LDS -> 3 blocks/CU co-resident (cross-block
// LDS||MFMA overlap), ~1.02 rounds. Per-wave 8 gloads/step; steady vmwait<16>, tail 8/0.
__global__ __launch_bounds__(128, 2) void conv_gemm(const unsigned short* __restrict__ Xt,
                                                    const unsigned short* __restrict__ Wp,
                                                    const float* __restrict__ bias,
                                                    float* __restrict__ out) {
  __shared__ __align__(1024) char smem[49152];  // ring of 3 x (A 8KB | B 8KB)
  const int t    = threadIdx.x;     // 0..127
  const int lane = t & 63;
  const int wid  = t >> 6;          // 0..1  (= wm; wn = 0)

  int bx = blockIdx.x;
  bx = (bx & 7) * 98 + (bx >> 3);   // XCD swizzle, bijective (784 = 8*98)
  const int mt  = bx & 1;
  const int spt = bx >> 1;          // 0..391

  // --- B staging: wave wid covers B rows wid*64 .. +63 via 4 gloads of 16 rows;
  //     lane -> row g*16+(lane>>2), LDS granule lane&3, source granule kgB (verified XOR).
  const int kgB = (lane & 3) ^ ((lane >> 3) & 3);
  const int Sb = spt * 128 + wid * 64 + (lane >> 2);
  const int S0 = Sb, S1 = Sb + 16, S2 = Sb + 32, S3 = Sb + 48;
  const int hw0 = S0 % PLANE, h0 = hw0 / HW_, w0 = hw0 - h0 * HW_;
  const int hw1 = S1 % PLANE, h1 = hw1 / HW_, w1 = hw1 - h1 * HW_;
  const int hw2 = S2 % PLANE, h2 = hw2 / HW_, w2 = hw2 - h2 * HW_;
  const int hw3 = S3 % PLANE, h3 = hw3 / HW_, w3 = hw3 - h3 * HW_;
  int vm0 = 0, vm1 = 0, vm2 = 0, vm3 = 0;
#pragma unroll
  for (int r = 0; r < 9; ++r) {
    int dh = r / 3 - 1, dw = r % 3 - 1;
    vm0 |= (int)(((unsigned)(h0 + dh) < HW_) & ((unsigned)(w0 + dw) < HW_)) << r;
    vm1 |= (int)(((unsigned)(h1 + dh) < HW_) & ((unsigned)(w1 + dw) < HW_)) << r;
    vm2 |= (int)(((unsigned)(h2 + dh) < HW_) & ((unsigned)(w2 + dw) < HW_)) << r;
    vm3 |= (int)(((unsigned)(h3 + dh) < HW_) & ((unsigned)(w3 + dw) < HW_)) << r;
  }
  const char* xb0 = (const char*)Xt + (size_t)S0 * 64 + kgB * 16;
  const char* xb1 = (const char*)Xt + (size_t)S1 * 64 + kgB * 16;
  const char* xb2 = (const char*)Xt + (size_t)S2 * 64 + kgB * 16;
  const char* xb3 = (const char*)Xt + (size_t)S3 * 64 + kgB * 16;
  const char* zb  = (const char*)(Wp + WP_USHORTS) + (lane & 3) * 16;
  // A source: sub-tile s block at (s*2+mt)*8192, linear; wave wid stages its half
  // via 4 gloads of 1KB: chunk = (wid*4+g)*64 + lane.
  const char* wpA = (const char*)Wp + mt * 8192 + wid * 4096 + lane * 16;

  // fragment read offsets (64B rows, granule swizzle kg^((row>>1)&3), lane-constant)
  const int swz  = ((lane >> 4) ^ ((lane >> 1) & 3)) * 16;
  const int aoff = (wid * 64 + (lane & 15)) * 64 + swz;          // + m*1024, m=0..3
  const int boff = 8192 + (lane & 15) * 64 + swz;                // + n*1024, n=0..7

  f32x4 acc[4][8];
  const f32x4 zf = {0.f, 0.f, 0.f, 0.f};
#pragma unroll
  for (int m = 0; m < 4; ++m)
#pragma unroll
    for (int n = 0; n < 8; ++n) acc[m][n] = zf;

  auto STAGE = [&](int s1) {
    char* buf = smem + (s1 % 3) * 16384;
    const int r = s1 >> 2, cb = s1 & 3;
    const int dh = r / 3 - 1, dw = r % 3 - 1;
    const long ro = (long)(dh * HW_ + dw) * 64 + (long)cb * PLSZ;
    const char* as = wpA + (size_t)(s1 * 2) * 8192;   // = (s1*2+mt)*8192 + wave/lane offs
    char* abuf = buf + wid * 4096;
#pragma unroll
    for (int g = 0; g < 4; ++g)
      gload16(abuf + g * 1024, as + g * 1024);        // A: wave half, linear chunks
    char* bbuf = buf + 8192 + wid * 4096;             // B rows wid*64..+63
    gload16(bbuf,        ((vm0 >> r) & 1) ? xb0 + ro : zb);
    gload16(bbuf + 1024, ((vm1 >> r) & 1) ? xb1 + ro : zb);
    gload16(bbuf + 2048, ((vm2 >> r) & 1) ? xb2 + ro : zb);
    gload16(bbuf + 3072, ((vm3 >> r) & 1) ? xb3 + ro : zb);
  };

  // prologue: 3 sub-tiles in flight (24 gloads/wave)
  STAGE(0); STAGE(1); STAGE(2);

#pragma unroll
  for (int s = 0; s < 36; ++s) {
    // counted wait: stage s's 8 loads (oldest) landed; 16 stay in flight. Never 0 mid-loop.
    if (s <= 33)      vmwait<16>();
    else if (s == 34) vmwait<8>();
    else              vmwait<0>();
    __builtin_amdgcn_s_barrier();      // stage-s data visible to both waves

    const char* rb = smem + (s % 3) * 16384;
    short8 a[4], b[8];
#pragma unroll
    for (int m = 0; m < 4; ++m) a[m] = *(const short8*)(rb + aoff + m * 1024);
#pragma unroll
    for (int n = 0; n < 8; ++n) b[n] = *(const short8*)(rb + boff + n * 1024);

    __builtin_amdgcn_s_setprio(1);
#pragma unroll
    for (int m = 0; m < 4; ++m)
#pragma unroll
      for (int n = 0; n < 8; ++n)
        acc[m][n] = __builtin_amdgcn_mfma_f32_16x16x32_bf16(a[m], b[n], acc[m][n], 0, 0, 0);
    __builtin_amdgcn_s_setprio(0);

    if (s < 33) {
      __builtin_amdgcn_s_barrier();    // both waves done reading buf[s%3] (WAR)
      STAGE(s + 3);
    }
  }

  // ---- epilogue: D row = co = (lane>>4)*4+reg, col = sp = lane&15
#pragma unroll
  for (int nf = 0; nf < 8; ++nf) {
    int S = spt * 128 + nf * 16 + (lane & 15);
    int nimg = S / PLANE, hw = S - nimg * PLANE;
    float* ob = out + (size_t)nimg * OUTN + hw;
#pragma unroll
    for (int mf = 0; mf < 4; ++mf) {
      int cob = mt * 128 + wid * 64 + mf * 16 + (lane >> 4) * 4;
#pragma unroll
      for (int r2 = 0; r2 < 4; ++r2)
        ob[(size_t)(cob + r2) * PLANE] = acc[mf][nf][r2] + bias[cob + r2];
    }
  }
}

// ---------------- fallback: naive direct conv (only if ws too small) ----------------
__global__ __launch_bounds__(256) void conv_naive(const float* __restrict__ X,
                                                  const float* __restrict__ W,
                                                  const float* __restrict__ bias,
                                                  float* __restrict__ out) {
  int idx = blockIdx.x * 256 + threadIdx.x;
  int hw = idx % PLANE;
  int co = (idx / PLANE) & 255;
  int n  = idx / (PLANE * 256);
  int h = hw / HW_, w = hw - h * HW_;
  float acc = bias[co];
  const float* xp = X + (size_t)n * CI * PLANE;
  const float* wp = W + (size_t)co * KTOT;
  for (int ci = 0; ci < CI; ++ci) {
#pragma unroll
    for (int kh = 0; kh < 3; ++kh) {
      int y = h + kh - 1;
      if ((unsigned)y >= HW_) continue;
#pragma unroll
      for (int kw = 0; kw < 3; ++kw) {
        int x = w + kw - 1;
        if ((unsigned)x >= HW_) continue;
        acc += xp[(size_t)ci * PLANE + y * HW_ + x] * wp[ci * 9 + kh * 3 + kw];
      }
    }
  }
  out[idx] = acc;
}

extern "C" void kernel_launch(void* const* d_in, const int* in_sizes, int n_in,
                              void* d_out, int out_size, void* d_ws, size_t ws_size,
                              hipStream_t stream) {
  (void)in_sizes; (void)n_in; (void)out_size;
  const float* X = (const float*)d_in[0];
  const float* W = (const float*)d_in[1];
  const float* b = (const float*)d_in[2];
  float* out = (float*)d_out;
  if (ws_size >= WS_NEED) {
    unsigned short* Xt = (unsigned short*)d_ws;
    unsigned short* Wp = (unsigned short*)((char*)d_ws + XT_BYTES);
    prep_fused<<<1744, 256, 0, stream>>>(X, W, Xt, Wp);
    conv_gemm<<<784, 128, 0, stream>>>(Xt, Wp, b, out);
  } else {
    conv_naive<<<(NB * CO_ * PLANE + 255) / 256, 256, 0, stream>>>(X, W, b, out);
  }
}

// Round 18
// 48.825 us; speedup vs baseline: 1.1836x; 1.1836x over previous
//
#include <hip/hip_runtime.h>

typedef __attribute__((ext_vector_type(8))) short short8;
typedef __attribute__((ext_vector_type(4))) float f32x4;

#define CI    128
#define CO_   256
#define HW_   56
#define PLANE 3136
#define NB    16
#define STOT  50176
#define KTOT  1152
#define OUTN  802816   // CO_*PLANE
#define PLSZ  3211264ull   // one cb-plane of Xt2: 50176 rows x 64 B

// ws layout: [0, 12845056) Xt2 bf16, 4 planes [cb][S][64B] ; [12845056, +589824) Wpre ; 256B zeros
#define XT_BYTES   12845056ull
#define WP_USHORTS 294912
#define WS_NEED    (12845056ull + 589824ull + 256ull)

__device__ __forceinline__ unsigned short f2bf(float f) {
  unsigned u = __float_as_uint(f);
  u += 0x7FFFu + ((u >> 16) & 1u);   // RNE
  return (unsigned short)(u >> 16);
}

__device__ __forceinline__ void gload16(void* lds, const void* g) {
  __builtin_amdgcn_global_load_lds(
      (const __attribute__((address_space(1))) unsigned int*)g,
      (__attribute__((address_space(3))) unsigned int*)lds, 16, 0, 0);
}

template <int N> __device__ __forceinline__ void vmwait() {
  asm volatile("s_waitcnt vmcnt(%0)" ::"n"(N) : "memory");
}

// ---------------- fused prep: blocks 0..1599 = prep_x ; 1600..1743 = prep_w ----------------
// (both byte-identical to the verified R12/R15/R16 kernels)
__global__ __launch_bounds__(256) void prep_fused(const float* __restrict__ X,
                                                  const float* __restrict__ W,
                                                  unsigned short* __restrict__ Xt,
                                                  unsigned short* __restrict__ Wp) {
  const int t = threadIdx.x;
  if (blockIdx.x < 1600) {
    __shared__ __align__(16) unsigned short tile[32][132];
    const int bx = blockIdx.x;
    const int n   = bx / 100;
    const int rem = bx % 100;
    const int cib = rem / 25;          // == cb plane
    const int spb = rem % 25;
    const int sp0 = spb * 128;
    const float* src = X + (size_t)(n * CI + cib * 32) * PLANE;
#pragma unroll
    for (int j = 0; j < 4; ++j) {
      int f = t + 256 * j;
      int ci  = f >> 5;
      int sp4 = (f & 31) * 4;
      if (sp0 + sp4 < PLANE) {
        f32x4 v = *(const f32x4*)(src + (size_t)ci * PLANE + sp0 + sp4);
#pragma unroll
        for (int e = 0; e < 4; ++e) tile[ci][sp4 + e] = f2bf(v[e]);
      }
    }
    __syncthreads();
    unsigned short* dstp = Xt + (size_t)cib * (PLSZ / 2) + ((size_t)n * PLANE + sp0) * 32;
#pragma unroll
    for (int j = 0; j < 2; ++j) {
      int g = t + 256 * j;
      int sp = g >> 2;
      int q  = g & 3;
      if (sp0 + sp < PLANE) {
        short8 v;
#pragma unroll
        for (int e = 0; e < 8; ++e) v[e] = (short)tile[q * 8 + e][sp];
        *(short8*)(dstp + (size_t)sp * 32 + q * 8) = v;
      }
    }
  } else {
    const int u = (blockIdx.x - 1600) * 256 + t;   // 0..36863
    const int rcbmt = u >> 9;
    const int p     = u & 511;
    const int mt  = rcbmt & 1;
    const int rcb = rcbmt >> 1;
    const int cb  = rcb & 3;
    const int r   = rcb >> 2;
    const int col = p >> 2;
    const int kg  = (p & 3) ^ ((col >> 1) & 3);
    const int co  = mt * 128 + col;
    const int ci0 = cb * 32 + kg * 8;
    short8 v;
#pragma unroll
    for (int e = 0; e < 8; ++e)
      v[e] = (short)f2bf(W[(size_t)co * KTOT + (size_t)(ci0 + e) * 9 + r]);
    *(short8*)(Wp + (size_t)u * 8) = v;
    if (u < 16) {
      short8 z = {0, 0, 0, 0, 0, 0, 0, 0};
      *(short8*)(Wp + WP_USHORTS + u * 8) = z;
    }
  }
}

// ---------------- conv_gemm: 128co x 256sp block, 4 waves of 64x128, ring-3, vmcnt(12) -------
// R16 (session best, reproduced): FLOP/LDS-byte 29.1 (wave tile 64x128). A path + swizzles
// verbatim R12; B staging 4 per-wave gloads (rows wid*64+j*16, same kgB XOR).
// LDS 72KB ring-3, 2 blocks/CU; grid 392 = 2 mt x 196 spt, bijective XCD swizzle (8x49).
__global__ __launch_bounds__(256, 2) void conv_gemm(const unsigned short* __restrict__ Xt,
                                                    const unsigned short* __restrict__ Wp,
                                                    const float* __restrict__ bias,
                                                    float* __restrict__ out) {
  __shared__ __align__(1024) char smem[73728];  // ring of 3 x (A 8KB | B 16KB)
  const int t    = threadIdx.x;
  const int lane = t & 63;
  const int wid  = t >> 6;
  const int wm   = wid >> 1, wn = wid & 1;

  int bx = blockIdx.x;
  bx = (bx & 7) * 49 + (bx >> 3);     // XCD swizzle, bijective (392 = 8*49)
  const int mt  = bx & 1;
  const int spt = bx >> 1;            // 0..195

  // --- B staging: wave stages rows wid*64 .. +63 via 4 gloads of 16 rows;
  //     lane -> row j*16+(lane>>2), LDS granule lane&3, source granule kgB (verified XOR).
  const int kgB = (lane & 3) ^ ((lane >> 3) & 3);
  const int Sb = spt * 256 + wid * 64 + (lane >> 2);
  const int S0 = Sb, S1 = Sb + 16, S2 = Sb + 32, S3 = Sb + 48;
  const int hw0 = S0 % PLANE, h0 = hw0 / HW_, w0 = hw0 - h0 * HW_;
  const int hw1 = S1 % PLANE, h1 = hw1 / HW_, w1 = hw1 - h1 * HW_;
  const int hw2 = S2 % PLANE, h2 = hw2 / HW_, w2 = hw2 - h2 * HW_;
  const int hw3 = S3 % PLANE, h3 = hw3 / HW_, w3 = hw3 - h3 * HW_;
  int vm0 = 0, vm1 = 0, vm2 = 0, vm3 = 0;
#pragma unroll
  for (int r = 0; r < 9; ++r) {
    int dh = r / 3 - 1, dw = r % 3 - 1;
    vm0 |= (int)(((unsigned)(h0 + dh) < HW_) & ((unsigned)(w0 + dw) < HW_)) << r;
    vm1 |= (int)(((unsigned)(h1 + dh) < HW_) & ((unsigned)(w1 + dw) < HW_)) << r;
    vm2 |= (int)(((unsigned)(h2 + dh) < HW_) & ((unsigned)(w2 + dw) < HW_)) << r;
    vm3 |= (int)(((unsigned)(h3 + dh) < HW_) & ((unsigned)(w3 + dw) < HW_)) << r;
  }
  const char* xb0 = (const char*)Xt + (size_t)S0 * 64 + kgB * 16;
  const char* xb1 = (const char*)Xt + (size_t)S1 * 64 + kgB * 16;
  const char* xb2 = (const char*)Xt + (size_t)S2 * 64 + kgB * 16;
  const char* xb3 = (const char*)Xt + (size_t)S3 * 64 + kgB * 16;
  const char* zb  = (const char*)(Wp + WP_USHORTS) + (lane & 3) * 16;
  const char* wpA = (const char*)Wp + mt * 8192 + t * 16;

  // fragment read offsets (64B rows, granule swizzle kg^((row>>1)&3), lane-constant)
  const int swz  = ((lane >> 4) ^ ((lane >> 1) & 3)) * 16;
  const int aoff = (wm * 64 + (lane & 15)) * 64 + swz;           // + m*1024, m=0..3
  const int boff = 8192 + (wn * 128 + (lane & 15)) * 64 + swz;   // + n*1024, n=0..7

  f32x4 acc[4][8];
  const f32x4 zf = {0.f, 0.f, 0.f, 0.f};
#pragma unroll
  for (int m = 0; m < 4; ++m)
#pragma unroll
    for (int n = 0; n < 8; ++n) acc[m][n] = zf;

  auto STAGE = [&](int s1) {
    char* buf = smem + (s1 % 3) * 24576;
    const int r = s1 >> 2, cb = s1 & 3;
    const int dh = r / 3 - 1, dw = r % 3 - 1;
    const long ro = (long)(dh * HW_ + dw) * 64 + (long)cb * PLSZ;
    const char* as = wpA + r * 65536 + cb * 16384;
    char* abuf = buf + wid * 1024;             // per-wave A slice (verified)
    gload16(abuf, as);                         // A rows: wave quarter of 0..63
    gload16(abuf + 4096, as + 4096);           // A rows: wave quarter of 64..127
    char* bbuf = buf + 8192 + wid * 4096;      // per-wave B slice: rows wid*64..+63
    gload16(bbuf,        ((vm0 >> r) & 1) ? xb0 + ro : zb);
    gload16(bbuf + 1024, ((vm1 >> r) & 1) ? xb1 + ro : zb);
    gload16(bbuf + 2048, ((vm2 >> r) & 1) ? xb2 + ro : zb);
    gload16(bbuf + 3072, ((vm3 >> r) & 1) ? xb3 + ro : zb);
  };

  // prologue: 3 sub-tiles in flight (18 gloads/wave)
  STAGE(0); STAGE(1); STAGE(2);

#pragma unroll
  for (int s = 0; s < 36; ++s) {
    // counted wait: stage s's 6 loads (oldest) landed; 12 stay in flight. Never 0 mid-loop.
    if (s <= 33)      vmwait<12>();
    else if (s == 34) vmwait<6>();
    else              vmwait<0>();
    __builtin_amdgcn_s_barrier();      // stage-s data visible to all waves

    const char* rb = smem + (s % 3) * 24576;
    short8 a[4], b[8];
#pragma unroll
    for (int m = 0; m < 4; ++m) a[m] = *(const short8*)(rb + aoff + m * 1024);
#pragma unroll
    for (int n = 0; n < 8; ++n) b[n] = *(const short8*)(rb + boff + n * 1024);

    __builtin_amdgcn_s_setprio(1);
#pragma unroll
    for (int m = 0; m < 4; ++m)
#pragma unroll
      for (int n = 0; n < 8; ++n)
        acc[m][n] = __builtin_amdgcn_mfma_f32_16x16x32_bf16(a[m], b[n], acc[m][n], 0, 0, 0);
    __builtin_amdgcn_s_setprio(0);

    if (s < 33) {
      __builtin_amdgcn_s_barrier();    // all waves done reading buf[s%3] (WAR)
      STAGE(s + 3);
    }
  }

  // ---- epilogue: D row = co = (lane>>4)*4+reg, col = sp = lane&15
#pragma unroll
  for (int nf = 0; nf < 8; ++nf) {
    int S = spt * 256 + wn * 128 + nf * 16 + (lane & 15);
    int nimg = S / PLANE, hw = S - nimg * PLANE;
    float* ob = out + (size_t)nimg * OUTN + hw;
#pragma unroll
    for (int mf = 0; mf < 4; ++mf) {
      int cob = mt * 128 + wm * 64 + mf * 16 + (lane >> 4) * 4;
#pragma unroll
      for (int r2 = 0; r2 < 4; ++r2)
        ob[(size_t)(cob + r2) * PLANE] = acc[mf][nf][r2] + bias[cob + r2];
    }
  }
}

// ---------------- fallback: naive direct conv (only if ws too small) ----------------
__global__ __launch_bounds__(256) void conv_naive(const float* __restrict__ X,
                                                  const float* __restrict__ W,
                                                  const float* __restrict__ bias,
                                                  float* __restrict__ out) {
  int idx = blockIdx.x * 256 + threadIdx.x;
  int hw = idx % PLANE;
  int co = (idx / PLANE) & 255;
  int n  = idx / (PLANE * 256);
  int h = hw / HW_, w = hw - h * HW_;
  float acc = bias[co];
  const float* xp = X + (size_t)n * CI * PLANE;
  const float* wp = W + (size_t)co * KTOT;
  for (int ci = 0; ci < CI; ++ci) {
#pragma unroll
    for (int kh = 0; kh < 3; ++kh) {
      int y = h + kh - 1;
      if ((unsigned)y >= HW_) continue;
#pragma unroll
      for (int kw = 0; kw < 3; ++kw) {
        int x = w + kw - 1;
        if ((unsigned)x >= HW_) continue;
        acc += xp[(size_t)ci * PLANE + y * HW_ + x] * wp[ci * 9 + kh * 3 + kw];
      }
    }
  }
  out[idx] = acc;
}

extern "C" void kernel_launch(void* const* d_in, const int* in_sizes, int n_in,
                              void* d_out, int out_size, void* d_ws, size_t ws_size,
                              hipStream_t stream) {
  (void)in_sizes; (void)n_in; (void)out_size;
  const float* X = (const float*)d_in[0];
  const float* W = (const float*)d_in[1];
  const float* b = (const float*)d_in[2];
  float* out = (float*)d_out;
  if (ws_size >= WS_NEED) {
    unsigned short* Xt = (unsigned short*)d_ws;
    unsigned short* Wp = (unsigned short*)((char*)d_ws + XT_BYTES);
    prep_fused<<<1744, 256, 0, stream>>>(X, W, Xt, Wp);
    conv_gemm<<<392, 256, 0, stream>>>(Xt, Wp, b, out);
  } else {
    conv_naive<<<(NB * CO_ * PLANE + 255) / 256, 256, 0, stream>>>(X, W, b, out);
  }
}